// Round 12
// baseline (36.802 us; speedup 1.0000x reference)
//
#include <hip/hip_runtime.h>
#include <math.h>

#define HALF_LOG_2PI_F 0.9189385332046727f

typedef float f32x4 __attribute__((ext_vector_type(4)));

// ---------------------------------------------------------------------------
// Kernel 1 (prep, single block of 1024): per-feature quadratic coefficients.
//   A[k] = deg * (-0.5 / s^2);  B[k] = deg * (m / s^2)
//   Csum = sum_k deg * (-0.5*m^2/s^2 - log(s) - HALF_LOG_2PI)
// ---------------------------------------------------------------------------
__global__ void clt_prep_kernel(const float* __restrict__ rp,
                                const int* __restrict__ edges,
                                float* __restrict__ A,
                                float* __restrict__ B,
                                float* __restrict__ csum,
                                int D, int E) {
    extern __shared__ float sdeg[];
    for (int k = threadIdx.x; k < D; k += blockDim.x) sdeg[k] = 0.0f;
    __syncthreads();
    for (int e = threadIdx.x; e < E; e += blockDim.x) {
        atomicAdd(&sdeg[edges[2 * e]], 1.0f);      // integer-valued: exact
        atomicAdd(&sdeg[edges[2 * e + 1]], 1.0f);
    }
    __syncthreads();
    float local_c = 0.0f;
    for (int k = threadIdx.x; k < D; k += blockDim.x) {
        float m = tanhf(rp[k]) * 2.0f;
        float sx = rp[D + k];
        float s = fmaxf(sx, 0.0f) + log1pf(expf(-fabsf(sx))) + 1e-6f;
        float inv_s2 = 1.0f / (s * s);
        float deg = sdeg[k];
        A[k] = deg * (-0.5f * inv_s2);
        B[k] = deg * (m * inv_s2);
        local_c += deg * (-0.5f * m * m * inv_s2 - logf(s) - HALF_LOG_2PI_F);
    }
    __shared__ float wsum[16];
    for (int off = 32; off > 0; off >>= 1)
        local_c += __shfl_down(local_c, off, 64);
    if ((threadIdx.x & 63) == 0) wsum[threadIdx.x >> 6] = local_c;
    __syncthreads();
    if (threadIdx.x == 0) {
        float t = 0.0f;
        int nw = (blockDim.x + 63) >> 6;
        for (int w = 0; w < nw; ++w) t += wsum[w];
        *csum = t;
    }
}

// ---------------------------------------------------------------------------
// Kernel 2 (main): slice/8-row decomposition of R10/R11, ONE change — x is
// staged into LDS via global_load_lds DMA (16 B/lane) instead of loaded to
// VGPRs. Tests whether the ~4.1 TB/s read plateau is the VMEM return-data
// path (DMA bypasses it) or a TCC/HBM read ceiling (DMA won't help).
//   Wave w owns columns [w*NI*256, (w+1)*NI*256); block b owns rows 8b..8b+7.
//   Stage: 8*NI DMA chunks of 1 KB into this wave's LDS segment (all in
//   flight), s_waitcnt vmcnt(0) (own-wave DMA -> no barrier needed).
//   Compute: ds_read_b128 + FMA per row, deferred interleaved reductions.
//   LDS: 4 waves * 8 rows * NI KB = 64 KB at NI=2 -> 2 blocks/CU.
// ---------------------------------------------------------------------------
template <int NI>
__global__ __launch_bounds__(256) void clt_dma(
        const float* __restrict__ x,
        const float* __restrict__ A,
        const float* __restrict__ B,
        const float* __restrict__ csum,
        float* __restrict__ out,
        int D) {
    const int lane = threadIdx.x & 63;
    const int w = threadIdx.x >> 6;            // slice id 0..3
    const int colbase = w * (NI * 64);         // slice start, float4 units

    __shared__ float smem[4][8 * NI * 256];    // per-wave segment, 1KB chunks
    __shared__ float lds[8][4];                // cross-wave combine

    const f32x4* Av = (const f32x4*)A;
    const f32x4* Bv = (const f32x4*)B;
    f32x4 a4[NI], b4[NI];
#pragma unroll
    for (int i = 0; i < NI; ++i) {
        a4[i] = Av[colbase + i * 64 + lane];
        b4[i] = Bv[colbase + i * 64 + lane];
    }
    const float c = *csum;

    const int r0 = blockIdx.x * 8;
    const float* gbase = x + (size_t)r0 * (size_t)D;

    // ---- stage: issue all 8*NI DMA chunks (each 64 lanes x 16 B = 1 KB) ----
#pragma unroll
    for (int r = 0; r < 8; ++r) {
#pragma unroll
        for (int i = 0; i < NI; ++i) {
            const float* g = gbase + (size_t)r * (size_t)D
                             + ((size_t)(colbase + i * 64 + lane) << 2);
            __builtin_amdgcn_global_load_lds(
                (const __attribute__((address_space(1))) unsigned int*)g,
                (__attribute__((address_space(3))) unsigned int*)
                    &smem[w][(r * NI + i) * 256],
                16, 0, 0);
        }
    }
    asm volatile("s_waitcnt vmcnt(0)" ::: "memory");

    // ---- compute from LDS ----
    float acc[8];
#pragma unroll
    for (int r = 0; r < 8; ++r) {
        float p = 0.0f, q = 0.0f;
#pragma unroll
        for (int i = 0; i < NI; ++i) {
            f32x4 xq = *(const f32x4*)&smem[w][(r * NI + i) * 256 + lane * 4];
            p += xq.x * fmaf(a4[i].x, xq.x, b4[i].x);
            q += xq.y * fmaf(a4[i].y, xq.y, b4[i].y);
            p += xq.z * fmaf(a4[i].z, xq.z, b4[i].z);
            q += xq.w * fmaf(a4[i].w, xq.w, b4[i].w);
        }
        acc[r] = p + q;
    }

    // ---- deferred interleaved reductions: 8 independent chains per level ----
#pragma unroll
    for (int off = 32; off > 0; off >>= 1) {
#pragma unroll
        for (int r = 0; r < 8; ++r)
            acc[r] += __shfl_down(acc[r], off, 64);
    }

    // ---- cross-wave combine ----
    if (lane == 0) {
#pragma unroll
        for (int r = 0; r < 8; ++r) lds[r][w] = acc[r];
    }
    __syncthreads();
    if (threadIdx.x < 8) {
        out[r0 + threadIdx.x] = lds[threadIdx.x][0] + lds[threadIdx.x][1]
                              + lds[threadIdx.x][2] + lds[threadIdx.x][3]
                              + c;
    }
}

// Generic fallback (any D): block-per-row.
__global__ __launch_bounds__(256) void clt_row_generic(
        const float* __restrict__ x,
        const float* __restrict__ A,
        const float* __restrict__ B,
        const float* __restrict__ csum,
        float* __restrict__ out,
        int D) {
    const int row = blockIdx.x;
    float acc = 0.0f;
    for (int k = threadIdx.x; k < D; k += blockDim.x) {
        float xs = x[(size_t)row * (size_t)D + k];
        acc += xs * fmaf(A[k], xs, B[k]);
    }
    for (int off = 32; off > 0; off >>= 1)
        acc += __shfl_down(acc, off, 64);
    __shared__ float wsum[4];
    if ((threadIdx.x & 63) == 0) wsum[threadIdx.x >> 6] = acc;
    __syncthreads();
    if (threadIdx.x == 0)
        out[row] = wsum[0] + wsum[1] + wsum[2] + wsum[3] + *csum;
}

extern "C" void kernel_launch(void* const* d_in, const int* in_sizes, int n_in,
                              void* d_out, int out_size, void* d_ws, size_t ws_size,
                              hipStream_t stream) {
    const float* x     = (const float*)d_in[0];
    const float* rp    = (const float*)d_in[1];
    const int*   edges = (const int*)d_in[2];
    float* out = (float*)d_out;

    const int D = in_sizes[1] / 2;       // 2048
    const int E = in_sizes[2] / 2;       // D-1
    const int N = out_size;              // 16384 rows

    float* A    = (float*)d_ws;          // [D]
    float* B    = A + D;                 // [D]
    float* csum = B + D;                 // [1]

    clt_prep_kernel<<<1, 1024, D * sizeof(float), stream>>>(rp, edges, A, B, csum, D, E);

    const int NI = D / 1024;             // float4s per lane per slice
    if (N % 8 == 0 && D == NI * 1024 && (NI == 1 || NI == 2)) {
        const int nblocks = N / 8;       // one 8-row batch per block (2048)
        switch (NI) {
            case 1:  clt_dma<1><<<nblocks, 256, 0, stream>>>(x, A, B, csum, out, D); break;
            default: clt_dma<2><<<nblocks, 256, 0, stream>>>(x, A, B, csum, out, D); break;
        }
    } else {
        clt_row_generic<<<N, 256, 0, stream>>>(x, A, B, csum, out, D);
    }
}

// Round 13
// 34.936 us; speedup vs baseline: 1.0534x; 1.0534x over previous
//
#include <hip/hip_runtime.h>
#include <math.h>

#define HALF_LOG_2PI_F 0.9189385332046727f

typedef float f32x4 __attribute__((ext_vector_type(4)));

// ---------------------------------------------------------------------------
// Kernel 1 (prep, single block of 1024): per-feature quadratic coefficients.
//   A[k] = deg * (-0.5 / s^2);  B[k] = deg * (m / s^2)
//   Csum = sum_k deg * (-0.5*m^2/s^2 - log(s) - HALF_LOG_2PI)
// ---------------------------------------------------------------------------
__global__ void clt_prep_kernel(const float* __restrict__ rp,
                                const int* __restrict__ edges,
                                float* __restrict__ A,
                                float* __restrict__ B,
                                float* __restrict__ csum,
                                int D, int E) {
    extern __shared__ float sdeg[];
    for (int k = threadIdx.x; k < D; k += blockDim.x) sdeg[k] = 0.0f;
    __syncthreads();
    for (int e = threadIdx.x; e < E; e += blockDim.x) {
        atomicAdd(&sdeg[edges[2 * e]], 1.0f);      // integer-valued: exact
        atomicAdd(&sdeg[edges[2 * e + 1]], 1.0f);
    }
    __syncthreads();
    float local_c = 0.0f;
    for (int k = threadIdx.x; k < D; k += blockDim.x) {
        float m = tanhf(rp[k]) * 2.0f;
        float sx = rp[D + k];
        float s = fmaxf(sx, 0.0f) + log1pf(expf(-fabsf(sx))) + 1e-6f;
        float inv_s2 = 1.0f / (s * s);
        float deg = sdeg[k];
        A[k] = deg * (-0.5f * inv_s2);
        B[k] = deg * (m * inv_s2);
        local_c += deg * (-0.5f * m * m * inv_s2 - logf(s) - HALF_LOG_2PI_F);
    }
    __shared__ float wsum[16];
    for (int off = 32; off > 0; off >>= 1)
        local_c += __shfl_down(local_c, off, 64);
    if ((threadIdx.x & 63) == 0) wsum[threadIdx.x >> 6] = local_c;
    __syncthreads();
    if (threadIdx.x == 0) {
        float t = 0.0f;
        int nw = (blockDim.x + 63) >> 6;
        for (int w = 0; w < nw; ++w) t += wsum[w];
        *csum = t;
    }
}

// ---------------------------------------------------------------------------
// Kernel 2 (main, D==2048 fixed): R11's slice8 structure, ONE change — x
// loads are inline-asm `global_load_dwordx4 ... sc0 sc1 nt` (system-scope,
// non-temporal). Probe: does scope-bypass skip MALL allocation and avoid
// victimizing the harness fills' dirty L3 lines (the writeback seen in R8's
// window)? FMAs are data-tied through the s_waitcnt asm (+v operands) so
// no consumer can be scheduled before the wait.
//   Wave w owns columns [w*512, w*512+512); block b owns rows 8b..8b+7.
// ---------------------------------------------------------------------------
__global__ __launch_bounds__(256) void clt_bypass(
        const float* __restrict__ x,
        const float* __restrict__ A,
        const float* __restrict__ B,
        const float* __restrict__ csum,
        float* __restrict__ out) {
    constexpr int NI = 2;          // float4 per lane per slice (D=2048)
    constexpr int ROWSTRIDE = 512; // float4 per row
    const int lane = threadIdx.x & 63;
    const int w = threadIdx.x >> 6;            // slice id 0..3
    const int colbase = w * (NI * 64);         // slice start, float4 units

    const f32x4* Av = (const f32x4*)A;
    const f32x4* Bv = (const f32x4*)B;
    f32x4 a4[NI], b4[NI];
#pragma unroll
    for (int i = 0; i < NI; ++i) {
        a4[i] = Av[colbase + i * 64 + lane];   // A/B cacheable (reused)
        b4[i] = Bv[colbase + i * 64 + lane];
    }
    const float c = *csum;

    const int r0 = blockIdx.x * 8;
    const f32x4* xv = (const f32x4*)(x + (size_t)r0 * 2048) + colbase + lane;

    // ---- issue all 16 bypass loads ----
    f32x4 xr[8][NI];
#pragma unroll
    for (int r = 0; r < 8; ++r) {
#pragma unroll
        for (int i = 0; i < NI; ++i) {
            const f32x4* p = xv + (size_t)r * ROWSTRIDE + i * 64;
            asm volatile("global_load_dwordx4 %0, %1, off sc0 sc1 nt"
                         : "=v"(xr[r][i]) : "v"(p) : "memory");
        }
    }
    // wait; tie every loaded value through the asm so consumers can't hoist
    asm volatile("s_waitcnt vmcnt(0)"
                 : "+v"(xr[0][0]), "+v"(xr[0][1]),
                   "+v"(xr[1][0]), "+v"(xr[1][1]),
                   "+v"(xr[2][0]), "+v"(xr[2][1]),
                   "+v"(xr[3][0]), "+v"(xr[3][1]),
                   "+v"(xr[4][0]), "+v"(xr[4][1]),
                   "+v"(xr[5][0]), "+v"(xr[5][1]),
                   "+v"(xr[6][0]), "+v"(xr[6][1]),
                   "+v"(xr[7][0]), "+v"(xr[7][1])
                 :: "memory");

    // ---- FMA dot per row ----
    float acc[8];
#pragma unroll
    for (int r = 0; r < 8; ++r) {
        float p = 0.0f, q = 0.0f;
#pragma unroll
        for (int i = 0; i < NI; ++i) {
            f32x4 xq = xr[r][i];
            p += xq.x * fmaf(a4[i].x, xq.x, b4[i].x);
            q += xq.y * fmaf(a4[i].y, xq.y, b4[i].y);
            p += xq.z * fmaf(a4[i].z, xq.z, b4[i].z);
            q += xq.w * fmaf(a4[i].w, xq.w, b4[i].w);
        }
        acc[r] = p + q;
    }

    // ---- deferred interleaved reductions ----
#pragma unroll
    for (int off = 32; off > 0; off >>= 1) {
#pragma unroll
        for (int r = 0; r < 8; ++r)
            acc[r] += __shfl_down(acc[r], off, 64);
    }

    // ---- cross-wave combine ----
    __shared__ float lds[8][4];
    if (lane == 0) {
#pragma unroll
        for (int r = 0; r < 8; ++r) lds[r][w] = acc[r];
    }
    __syncthreads();
    if (threadIdx.x < 8) {
        out[r0 + threadIdx.x] = lds[threadIdx.x][0] + lds[threadIdx.x][1]
                              + lds[threadIdx.x][2] + lds[threadIdx.x][3]
                              + c;
    }
}

// Generic fallback (any D): block-per-row.
__global__ __launch_bounds__(256) void clt_row_generic(
        const float* __restrict__ x,
        const float* __restrict__ A,
        const float* __restrict__ B,
        const float* __restrict__ csum,
        float* __restrict__ out,
        int D) {
    const int row = blockIdx.x;
    float acc = 0.0f;
    for (int k = threadIdx.x; k < D; k += blockDim.x) {
        float xs = x[(size_t)row * (size_t)D + k];
        acc += xs * fmaf(A[k], xs, B[k]);
    }
    for (int off = 32; off > 0; off >>= 1)
        acc += __shfl_down(acc, off, 64);
    __shared__ float wsum[4];
    if ((threadIdx.x & 63) == 0) wsum[threadIdx.x >> 6] = acc;
    __syncthreads();
    if (threadIdx.x == 0)
        out[row] = wsum[0] + wsum[1] + wsum[2] + wsum[3] + *csum;
}

extern "C" void kernel_launch(void* const* d_in, const int* in_sizes, int n_in,
                              void* d_out, int out_size, void* d_ws, size_t ws_size,
                              hipStream_t stream) {
    const float* x     = (const float*)d_in[0];
    const float* rp    = (const float*)d_in[1];
    const int*   edges = (const int*)d_in[2];
    float* out = (float*)d_out;

    const int D = in_sizes[1] / 2;       // 2048
    const int E = in_sizes[2] / 2;       // D-1
    const int N = out_size;              // 16384 rows

    float* A    = (float*)d_ws;          // [D]
    float* B    = A + D;                 // [D]
    float* csum = B + D;                 // [1]

    clt_prep_kernel<<<1, 1024, D * sizeof(float), stream>>>(rp, edges, A, B, csum, D, E);

    if (D == 2048 && N % 8 == 0) {
        const int nblocks = N / 8;       // 2048 blocks, one 8-row batch each
        clt_bypass<<<nblocks, 256, 0, stream>>>(x, A, B, csum, out);
    } else {
        clt_row_generic<<<N, 256, 0, stream>>>(x, A, B, csum, out, D);
    }
}

// Round 14
// 33.501 us; speedup vs baseline: 1.0985x; 1.0428x over previous
//
#include <hip/hip_runtime.h>
#include <math.h>

#define HALF_LOG_2PI_F 0.9189385332046727f

typedef float f32x4 __attribute__((ext_vector_type(4)));

// ---------------------------------------------------------------------------
// Kernel 1 (prep, single block of 1024): per-feature quadratic coefficients.
//   A[k] = deg * (-0.5 / s^2);  B[k] = deg * (m / s^2)
//   Csum = sum_k deg * (-0.5*m^2/s^2 - log(s) - HALF_LOG_2PI)
// ---------------------------------------------------------------------------
__global__ void clt_prep_kernel(const float* __restrict__ rp,
                                const int* __restrict__ edges,
                                float* __restrict__ A,
                                float* __restrict__ B,
                                float* __restrict__ csum,
                                int D, int E) {
    extern __shared__ float sdeg[];
    for (int k = threadIdx.x; k < D; k += blockDim.x) sdeg[k] = 0.0f;
    __syncthreads();
    for (int e = threadIdx.x; e < E; e += blockDim.x) {
        atomicAdd(&sdeg[edges[2 * e]], 1.0f);      // integer-valued: exact
        atomicAdd(&sdeg[edges[2 * e + 1]], 1.0f);
    }
    __syncthreads();
    float local_c = 0.0f;
    for (int k = threadIdx.x; k < D; k += blockDim.x) {
        float m = tanhf(rp[k]) * 2.0f;
        float sx = rp[D + k];
        float s = fmaxf(sx, 0.0f) + log1pf(expf(-fabsf(sx))) + 1e-6f;
        float inv_s2 = 1.0f / (s * s);
        float deg = sdeg[k];
        A[k] = deg * (-0.5f * inv_s2);
        B[k] = deg * (m * inv_s2);
        local_c += deg * (-0.5f * m * m * inv_s2 - logf(s) - HALF_LOG_2PI_F);
    }
    __shared__ float wsum[16];
    for (int off = 32; off > 0; off >>= 1)
        local_c += __shfl_down(local_c, off, 64);
    if ((threadIdx.x & 63) == 0) wsum[threadIdx.x >> 6] = local_c;
    __syncthreads();
    if (threadIdx.x == 0) {
        float t = 0.0f;
        int nw = (blockDim.x + 63) >> 6;
        for (int w = 0; w < nw; ++w) t += wsum[w];
        *csum = t;
    }
}

// ---------------------------------------------------------------------------
// Kernel 2 (main): R11's slice8 + nontemporal loads, ONE change — the
// block -> row-batch mapping is SWIZZLED so the ~512 co-resident blocks
// span the entire x buffer (256 KB granularity) instead of a contiguous
// ~32 MB sliding window. Theory: the 7 TB/s fills have a full-buffer
// instantaneous footprint (grid-stride); if the ~4.1 TB/s read plateau is
// DRAM-bank/MALL-set concentration of a narrow window, spreading fixes it.
//   batch = (bid & 511)*4 + (bid >> 9)   (bijective on [0,2048))
// ---------------------------------------------------------------------------
template <int NI>
__global__ __launch_bounds__(256) void clt_slice8sw(
        const float* __restrict__ x,
        const float* __restrict__ A,
        const float* __restrict__ B,
        const float* __restrict__ csum,
        float* __restrict__ out,
        int D, int nblocks) {
    const int lane = threadIdx.x & 63;
    const int w = threadIdx.x >> 6;            // slice id 0..3
    const int colbase = w * (NI * 64);         // slice start, float4 units
    const int rowstride = D >> 2;              // float4 per row

    const f32x4* Av = (const f32x4*)A;
    const f32x4* Bv = (const f32x4*)B;
    f32x4 a4[NI], b4[NI];
#pragma unroll
    for (int i = 0; i < NI; ++i) {
        a4[i] = Av[colbase + i * 64 + lane];   // A/B cacheable (reused)
        b4[i] = Bv[colbase + i * 64 + lane];
    }
    const float c = *csum;

    // footprint swizzle (bijective when nblocks == 2048)
    int batch = blockIdx.x;
    if (nblocks == 2048)
        batch = ((blockIdx.x & 511) << 2) | (blockIdx.x >> 9);

    const int r0 = batch * 8;
    const f32x4* xv = (const f32x4*)(x + (size_t)r0 * (size_t)D)
                      + colbase + lane;

    // Phase 1: all loads first (nontemporal), then FMAs.
    f32x4 xr[8][NI];
#pragma unroll
    for (int r = 0; r < 8; ++r)
#pragma unroll
        for (int i = 0; i < NI; ++i)
            xr[r][i] = __builtin_nontemporal_load(&xv[(size_t)r * rowstride + i * 64]);

    float acc[8];
#pragma unroll
    for (int r = 0; r < 8; ++r) {
        float p = 0.0f, q = 0.0f;
#pragma unroll
        for (int i = 0; i < NI; ++i) {
            f32x4 xq = xr[r][i];
            p += xq.x * fmaf(a4[i].x, xq.x, b4[i].x);
            q += xq.y * fmaf(a4[i].y, xq.y, b4[i].y);
            p += xq.z * fmaf(a4[i].z, xq.z, b4[i].z);
            q += xq.w * fmaf(a4[i].w, xq.w, b4[i].w);
        }
        acc[r] = p + q;
    }

    // Phase 2: interleaved reductions — 8 independent chains per level.
#pragma unroll
    for (int off = 32; off > 0; off >>= 1) {
#pragma unroll
        for (int r = 0; r < 8; ++r)
            acc[r] += __shfl_down(acc[r], off, 64);
    }

    // Phase 3: cross-wave combine via tiny LDS.
    __shared__ float lds[8][4];
    if (lane == 0) {
#pragma unroll
        for (int r = 0; r < 8; ++r) lds[r][w] = acc[r];
    }
    __syncthreads();
    if (threadIdx.x < 8) {
        out[r0 + threadIdx.x] = lds[threadIdx.x][0] + lds[threadIdx.x][1]
                              + lds[threadIdx.x][2] + lds[threadIdx.x][3]
                              + c;
    }
}

// Generic fallback (any D): block-per-row.
__global__ __launch_bounds__(256) void clt_row_generic(
        const float* __restrict__ x,
        const float* __restrict__ A,
        const float* __restrict__ B,
        const float* __restrict__ csum,
        float* __restrict__ out,
        int D) {
    const int row = blockIdx.x;
    float acc = 0.0f;
    for (int k = threadIdx.x; k < D; k += blockDim.x) {
        float xs = x[(size_t)row * (size_t)D + k];
        acc += xs * fmaf(A[k], xs, B[k]);
    }
    for (int off = 32; off > 0; off >>= 1)
        acc += __shfl_down(acc, off, 64);
    __shared__ float wsum[4];
    if ((threadIdx.x & 63) == 0) wsum[threadIdx.x >> 6] = acc;
    __syncthreads();
    if (threadIdx.x == 0)
        out[row] = wsum[0] + wsum[1] + wsum[2] + wsum[3] + *csum;
}

extern "C" void kernel_launch(void* const* d_in, const int* in_sizes, int n_in,
                              void* d_out, int out_size, void* d_ws, size_t ws_size,
                              hipStream_t stream) {
    const float* x     = (const float*)d_in[0];
    const float* rp    = (const float*)d_in[1];
    const int*   edges = (const int*)d_in[2];
    float* out = (float*)d_out;

    const int D = in_sizes[1] / 2;       // 2048
    const int E = in_sizes[2] / 2;       // D-1
    const int N = out_size;              // 16384 rows

    float* A    = (float*)d_ws;          // [D]
    float* B    = A + D;                 // [D]
    float* csum = B + D;                 // [1]

    clt_prep_kernel<<<1, 1024, D * sizeof(float), stream>>>(rp, edges, A, B, csum, D, E);

    const int NI = D / 1024;             // float4s per lane per slice
    if (N % 8 == 0 && D == NI * 1024 && (NI == 1 || NI == 2 || NI == 4)) {
        const int nblocks = N / 8;       // one 8-row batch per block (2048)
        switch (NI) {
            case 1:  clt_slice8sw<1><<<nblocks, 256, 0, stream>>>(x, A, B, csum, out, D, nblocks); break;
            case 2:  clt_slice8sw<2><<<nblocks, 256, 0, stream>>>(x, A, B, csum, out, D, nblocks); break;
            default: clt_slice8sw<4><<<nblocks, 256, 0, stream>>>(x, A, B, csum, out, D, nblocks); break;
        }
    } else {
        clt_row_generic<<<N, 256, 0, stream>>>(x, A, B, csum, out, D);
    }
}